// Round 10
// baseline (1243.325 us; speedup 1.0000x reference)
//
#include <hip/hip_runtime.h>
#include <hip/hip_bf16.h>

constexpr int N = 16384;   // points
constexpr int KNN = 10;
constexpr int CF = 64;     // feature channels per edgeconv
constexpr int NS64 = 12;   // col splits for knn64 (grid 64*12 = 768 = 3 blocks/CU)
constexpr int NS3 = 12;    // col splits for knn3  (grid 64*12 = 768)

#define FBIG 1e30f

typedef __attribute__((ext_vector_type(8))) __bf16 bfv8;
typedef __attribute__((ext_vector_type(4))) float f32x4;

// ---------- top-k insert (replace-max) ----------
#define TOPK_INSERT(dval, jval)                                            \
  if ((dval) < bmax) {                                                     \
    float mv = bd[0]; int slot = 0;                                        \
    _Pragma("unroll") for (int s_ = 1; s_ < 10; ++s_)                      \
      if (bd[s_] > mv) { mv = bd[s_]; slot = s_; }                         \
    _Pragma("unroll") for (int s_ = 0; s_ < 10; ++s_)                      \
      if (slot == s_) { bd[s_] = (dval); bi[s_] = (jval); }                \
    bmax = bd[0];                                                          \
    _Pragma("unroll") for (int s_ = 1; s_ < 10; ++s_)                      \
      bmax = fmaxf(bmax, bd[s_]);                                          \
  }

__device__ inline ushort bf16_rne(float x) {
  unsigned u = __float_as_uint(x);
  return (ushort)((u + 0x7FFFu + ((u >> 16) & 1u)) >> 16);
}
__device__ inline float bf16_to_f(ushort h) { return __uint_as_float(((unsigned)h) << 16); }

// ---------- pack x (3ch) into float4 with sq norm; init gtau + accum ----------
__global__ __launch_bounds__(256) void pack3_kernel(const float* __restrict__ X,
                                                    float4* __restrict__ xp,
                                                    int* __restrict__ gtauI,
                                                    float* __restrict__ accum) {
  int i = blockIdx.x * 256 + threadIdx.x;
  float x0 = X[3 * i], x1 = X[3 * i + 1], x2 = X[3 * i + 2];
  float s = fmaf(x0, x0, fmaf(x1, x1, x2 * x2));
  xp[i] = make_float4(x0, x1, x2, s);
  gtauI[i] = 0x7F7F7F7F;  // ~3.39e38
  if (blockIdx.x == 0 && threadIdx.x < 128) accum[threadIdx.x] = 0.f;
}

// ---------- kNN for C=64 via bf16-split MFMA: 32-col chunks (r13-banked, 213us) ----------
// r0-VERBATIM structure + r9 s_setprio bracket around MFMA clusters (T5, -3.5us/call).
// Session ledger:
//  r14: __launch_bounds__(256,4) caps 64 VGPR -> pinned A-frags demoted, A
//       re-streamed from global (FETCH 34MB->1.37GB, 765us). Keep (256,3).
//  r1:  folding sq into MFMA via meta-fragment (384B rows) -> dependent-chain +
//       stream-pattern break, 308us. Keep 256B rows + zero-seeded acc.
//  r2:  acc seeded with -0.5*sq_j + thr-compare -> load on MFMA critical path,
//       297us. Keep epilogue fmaf(-2,acc,sqi+sj).
//  r3:  per-lane register top-k (swapped operands) -> 4x column traffic + exec-
//       unioned insert storms, 667us. Keep batch LDS buffer + drain.
//  r5:  half-chunk drains (cap 17, NS=16) -> 2x drain/barrier fixed cost, 281us.
//       Keep single drain per 32-col chunk, capacity 33, NS=12.
//  r6:  streaming-insert merge (1-wave blocks) -> serial dep chain, +46us total.
//  r7:  uv 16-pt blocking -> +36us/call. Keep 4-pt uv.
//  r8:  prep128s fused into apply (bit-identical) -> -23us. WIN.
//  r9:  s_setprio around MFMA cluster -> -10us total. WIN. (absmax tie-flips to
//       0.0015869: gtau race timing changes resolve (d,id) boundary ties
//       differently; both outcomes valid & passing.)
__global__ __launch_bounds__(256, 3) void knn64w_kernel(const ushort* __restrict__ Xp,
                                                        const float* __restrict__ sq,
                                                        int* __restrict__ gtauI,
                                                        float* __restrict__ dpart,
                                                        ushort* __restrict__ ipart) {
  __shared__ float bufD[4][64 * 33];
  __shared__ ushort bufI[4][64 * 34];
  __shared__ __align__(16) float tauS[4][64];
  __shared__ int cntS[4][64];

  const int tid = threadIdx.x;
  const int w = tid >> 6, l = tid & 63, lp = l & 15, g = l >> 4;
  const int rg = blockIdx.x / NS64, cs = blockIdx.x % NS64;
  const int wbase = rg * 256 + w * 64;
  const int myrow = wbase + l;
  const int c0 = (512 * cs) / NS64, c1 = (512 * (cs + 1)) / NS64;  // 32-col chunks

  tauS[w][l] = FBIG;
  cntS[w][l] = 0;
  __builtin_amdgcn_wave_barrier();

  // A fragments: 4 row-tiles (rows wbase + rt*16 + lp, k-slice g*8)
  bfv8 aH1[4], aH2[4], aL1[4], aL2[4];
#pragma unroll
  for (int rt = 0; rt < 4; ++rt) {
    const size_t ao = (size_t)(wbase + rt * 16 + lp) * 128 + g * 8;
    aH1[rt] = *(const bfv8*)&Xp[ao];
    aH2[rt] = *(const bfv8*)&Xp[ao + 32];
    aL1[rt] = *(const bfv8*)&Xp[ao + 64];
    aL2[rt] = *(const bfv8*)&Xp[ao + 96];
  }
  float sqi[16];
#pragma unroll
  for (int rt = 0; rt < 4; ++rt)
#pragma unroll
    for (int r = 0; r < 4; ++r) sqi[rt * 4 + r] = sq[wbase + rt * 16 + g * 4 + r];

  float bd[10]; int bi[10]; float bmax = FBIG; float lastPub = FBIG;
#pragma unroll
  for (int s = 0; s < 10; ++s) { bd[s] = FBIG; bi[s] = 0x7fffffff; }
  int gt = 0x7F7F7F7F;

  for (int t = c0; t < c1; ++t) {
    const int col0 = t * 32 + lp;
    const int col1 = col0 + 16;
    const size_t bo0 = (size_t)col0 * 128 + g * 8;
    bfv8 p0 = *(const bfv8*)&Xp[bo0];
    bfv8 p1 = *(const bfv8*)&Xp[bo0 + 32];
    bfv8 p2 = *(const bfv8*)&Xp[bo0 + 64];
    bfv8 p3 = *(const bfv8*)&Xp[bo0 + 96];
    const size_t bo1 = (size_t)col1 * 128 + g * 8;
    bfv8 q0 = *(const bfv8*)&Xp[bo1];
    bfv8 q1 = *(const bfv8*)&Xp[bo1 + 32];
    bfv8 q2 = *(const bfv8*)&Xp[bo1 + 64];
    bfv8 q3 = *(const bfv8*)&Xp[bo1 + 96];
    float sj0 = sq[col0];
    float sj1 = sq[col1];
    int gtn = gtauI[myrow];

    __builtin_amdgcn_wave_barrier();
    {  // drain prev chunk: every lane owns row l   (prio 0: VALU/LDS phase)
      const int c = cntS[w][l];
      if (c) {
        const float* bD = &bufD[w][l * 33];
        const ushort* bI = &bufI[w][l * 34];
#pragma unroll 1
        for (int j = 0; j < c; ++j) {
          float d = bD[j];
          int ii = (int)bI[j];
          TOPK_INSERT(d, ii);
        }
        cntS[w][l] = 0;
      }
      tauS[w][l] = fminf(bmax, __int_as_float(gt));
      if (bmax < lastPub) {  // publish only on improvement
        atomicMin(&gtauI[myrow], __float_as_int(bmax));
        lastPub = bmax;
      }
    }
    __builtin_amdgcn_wave_barrier();
    gt = gtn;

#pragma unroll
    for (int rt = 0; rt < 4; ++rt) {
      f32x4 taur = *(const f32x4*)&tauS[w][rt * 16 + g * 4];
      __builtin_amdgcn_s_setprio(1);  // MFMA cluster: favor this wave's issue
      f32x4 acc0 = {0.f, 0.f, 0.f, 0.f};
      acc0 = __builtin_amdgcn_mfma_f32_16x16x32_bf16(aH1[rt], p0, acc0, 0, 0, 0);
      acc0 = __builtin_amdgcn_mfma_f32_16x16x32_bf16(aH2[rt], p1, acc0, 0, 0, 0);
      acc0 = __builtin_amdgcn_mfma_f32_16x16x32_bf16(aH1[rt], p2, acc0, 0, 0, 0);
      acc0 = __builtin_amdgcn_mfma_f32_16x16x32_bf16(aH2[rt], p3, acc0, 0, 0, 0);
      acc0 = __builtin_amdgcn_mfma_f32_16x16x32_bf16(aL1[rt], p0, acc0, 0, 0, 0);
      acc0 = __builtin_amdgcn_mfma_f32_16x16x32_bf16(aL2[rt], p1, acc0, 0, 0, 0);
      f32x4 acc1 = {0.f, 0.f, 0.f, 0.f};
      acc1 = __builtin_amdgcn_mfma_f32_16x16x32_bf16(aH1[rt], q0, acc1, 0, 0, 0);
      acc1 = __builtin_amdgcn_mfma_f32_16x16x32_bf16(aH2[rt], q1, acc1, 0, 0, 0);
      acc1 = __builtin_amdgcn_mfma_f32_16x16x32_bf16(aH1[rt], q2, acc1, 0, 0, 0);
      acc1 = __builtin_amdgcn_mfma_f32_16x16x32_bf16(aH2[rt], q3, acc1, 0, 0, 0);
      acc1 = __builtin_amdgcn_mfma_f32_16x16x32_bf16(aL1[rt], q0, acc1, 0, 0, 0);
      acc1 = __builtin_amdgcn_mfma_f32_16x16x32_bf16(aL2[rt], q1, acc1, 0, 0, 0);
      __builtin_amdgcn_s_setprio(0);  // epilogue/insert storm: yield issue
#pragma unroll
      for (int r = 0; r < 4; ++r) {
        const int rloc = rt * 16 + g * 4 + r;
        float d0 = fmaf(-2.f, acc0[r], sqi[rt * 4 + r] + sj0);
        if (d0 < taur[r]) {
          int pos = atomicAdd(&cntS[w][rloc], 1);
          bufD[w][rloc * 33 + pos] = d0;
          bufI[w][rloc * 34 + pos] = (ushort)col0;
        }
        float d1 = fmaf(-2.f, acc1[r], sqi[rt * 4 + r] + sj1);
        if (d1 < taur[r]) {
          int pos = atomicAdd(&cntS[w][rloc], 1);
          bufD[w][rloc * 33 + pos] = d1;
          bufI[w][rloc * 34 + pos] = (ushort)col1;
        }
      }
    }
  }

  __builtin_amdgcn_wave_barrier();
  {  // final drain
    const int c = cntS[w][l];
    const float* bD = &bufD[w][l * 33];
    const ushort* bI = &bufI[w][l * 34];
#pragma unroll 1
    for (int j = 0; j < c; ++j) {
      float d = bD[j];
      int ii = (int)bI[j];
      TOPK_INSERT(d, ii);
    }
  }
  float* dp = dpart + ((size_t)cs * N + myrow) * 10;
  ushort* ip = ipart + ((size_t)cs * N + myrow) * 10;
#pragma unroll
  for (int s = 0; s < 10; ++s) { dp[s] = bd[s]; ip[s] = (ushort)bi[s]; }
}

// ---------- kNN for C=3, exact fp32 (cancellation-sensitive: keep fp32!) ----------
// VERBATIM r0 structure: 32-col chunks, single drain, capacity 33.
__global__ __launch_bounds__(256, 3) void knn3g_kernel(const float4* __restrict__ xp,
                                                       int* __restrict__ gtauI,
                                                       float* __restrict__ dpart,
                                                       ushort* __restrict__ ipart) {
  __shared__ float bufD[4][64 * 33];
  __shared__ ushort bufI[4][64 * 34];
  __shared__ __align__(16) float tauS[4][64];
  __shared__ int cntS[4][64];

  const int tid = threadIdx.x;
  const int w = tid >> 6, l = tid & 63, lp = l & 15, g = l >> 4;
  const int rg = blockIdx.x / NS3, cs = blockIdx.x % NS3;
  const int wbase = rg * 256 + w * 64;
  const int myrow = wbase + l;
  const int c0 = (512 * cs) / NS3, c1 = (512 * (cs + 1)) / NS3;  // 32-col chunks

  tauS[w][l] = FBIG;
  cntS[w][l] = 0;
  __builtin_amdgcn_wave_barrier();

  float4 rw[16];
#pragma unroll
  for (int rt = 0; rt < 4; ++rt)
#pragma unroll
    for (int r = 0; r < 4; ++r) rw[rt * 4 + r] = xp[wbase + rt * 16 + g * 4 + r];

  float bd[10]; int bi[10]; float bmax = FBIG; float lastPub = FBIG;
#pragma unroll
  for (int s = 0; s < 10; ++s) { bd[s] = FBIG; bi[s] = 0x7fffffff; }
  int gt = 0x7F7F7F7F;

  for (int t = c0; t < c1; ++t) {
    const int col0 = t * 32 + lp;
    const int col1 = col0 + 16;
    const float4 oc0 = xp[col0];
    const float4 oc1 = xp[col1];
    int gtn = gtauI[myrow];

    __builtin_amdgcn_wave_barrier();
    {  // drain prev chunk
      const int c = cntS[w][l];
      if (c) {
        const float* bD = &bufD[w][l * 33];
        const ushort* bI = &bufI[w][l * 34];
#pragma unroll 1
        for (int j = 0; j < c; ++j) {
          float d = bD[j];
          int ii = (int)bI[j];
          TOPK_INSERT(d, ii);
        }
        cntS[w][l] = 0;
      }
      tauS[w][l] = fminf(bmax, __int_as_float(gt));
      if (bmax < lastPub) {
        atomicMin(&gtauI[myrow], __float_as_int(bmax));
        lastPub = bmax;
      }
    }
    __builtin_amdgcn_wave_barrier();
    gt = gtn;

#pragma unroll
    for (int rt = 0; rt < 4; ++rt) {
      f32x4 taur = *(const f32x4*)&tauS[w][rt * 16 + g * 4];
#pragma unroll
      for (int r = 0; r < 4; ++r) {
        const float4 m = rw[rt * 4 + r];
        const int rloc = rt * 16 + g * 4 + r;
        float dot0 = fmaf(m.x, oc0.x, fmaf(m.y, oc0.y, m.z * oc0.z));
        float d0 = fmaf(-2.f, dot0, m.w + oc0.w);  // same chain as validated knn3
        if (d0 < taur[r]) {
          int pos = atomicAdd(&cntS[w][rloc], 1);
          bufD[w][rloc * 33 + pos] = d0;
          bufI[w][rloc * 34 + pos] = (ushort)col0;
        }
        float dot1 = fmaf(m.x, oc1.x, fmaf(m.y, oc1.y, m.z * oc1.z));
        float d1 = fmaf(-2.f, dot1, m.w + oc1.w);
        if (d1 < taur[r]) {
          int pos = atomicAdd(&cntS[w][rloc], 1);
          bufD[w][rloc * 33 + pos] = d1;
          bufI[w][rloc * 34 + pos] = (ushort)col1;
        }
      }
    }
  }

  __builtin_amdgcn_wave_barrier();
  {  // final drain
    const int c = cntS[w][l];
    const float* bD = &bufD[w][l * 33];
    const ushort* bI = &bufI[w][l * 34];
#pragma unroll 1
    for (int j = 0; j < c; ++j) {
      float d = bD[j];
      int ii = (int)bI[j];
      TOPK_INSERT(d, ii);
    }
  }
  float* dp = dpart + ((size_t)cs * N + myrow) * 10;
  ushort* ip = ipart + ((size_t)cs * N + myrow) * 10;
#pragma unroll
  for (int s = 0; s < 10; ++s) { dp[s] = bd[s]; ip[s] = (ushort)bi[s]; }
}

// ---------- merge S partial top-10 lists per row (r10: hierarchical, no spill) ----------
// r0's flat version held d[120]+id[120] (~240 values) -> scratch spill; the 10
// selection passes re-scanned ~480B/thread/pass FROM SCRATCH (~78MB traffic/call).
// r10: 4 groups of 3 lists; per group load 30 pairs into REGISTERS (peak ~112
// VGPR, statically indexed, no spill) and select the lex-(d,id)-smallest 10 of
// running(10) ∪ group(30). EXACT same output as the flat version: ids are
// globally distinct across splits -> (d,id) is a strict total order, and
// top10(A∪B) ⊆ top10(A)∪top10(B) makes the hierarchy pick the identical 10,
// emitted in the same sorted order. (r6 lesson: do NOT serialize inserts —
// this keeps the flat version's parallel selection-pass structure.)
template <int S>
__global__ __launch_bounds__(256) void merge_kernel(const float* __restrict__ dpart,
                                                    const ushort* __restrict__ ipart,
                                                    ushort* __restrict__ idx_out) {
  static_assert(S % 3 == 0, "S must be divisible by group size 3");
  constexpr int G = 3;
  constexpr int NG = S / G;
  const int row = blockIdx.x * 256 + threadIdx.x;
  float rd[10]; int ri[10];
#pragma unroll
  for (int s = 0; s < 10; ++s) { rd[s] = FBIG; ri[s] = 0x7fffffff; }
#pragma unroll 1
  for (int gidx = 0; gidx < NG; ++gidx) {
    float gd[G * 10]; int gi[G * 10];
#pragma unroll
    for (int p = 0; p < G; ++p)
#pragma unroll
      for (int s = 0; s < 10; ++s) {
        gd[p * 10 + s] = dpart[((size_t)(gidx * G + p) * N + row) * 10 + s];
        gi[p * 10 + s] = (int)ipart[((size_t)(gidx * G + p) * N + row) * 10 + s];
      }
    float nd[10]; int ni[10];
#pragma unroll
    for (int t = 0; t < 10; ++t) {
      float dm = rd[0]; int im = ri[0]; int slot = 0;  // slot<10: rd; else gd
#pragma unroll
      for (int e = 1; e < 10; ++e) {
        bool better = (rd[e] < dm) || (rd[e] == dm && ri[e] < im);
        if (better) { dm = rd[e]; im = ri[e]; slot = e; }
      }
#pragma unroll
      for (int e = 0; e < G * 10; ++e) {
        bool better = (gd[e] < dm) || (gd[e] == dm && gi[e] < im);
        if (better) { dm = gd[e]; im = gi[e]; slot = 10 + e; }
      }
      nd[t] = dm; ni[t] = im;
#pragma unroll
      for (int e = 0; e < 10; ++e)
        if (slot == e) rd[e] = FBIG;
#pragma unroll
      for (int e = 0; e < G * 10; ++e)
        if (slot == 10 + e) gd[e] = FBIG;
    }
#pragma unroll
    for (int t = 0; t < 10; ++t) { rd[t] = nd[t]; ri[t] = ni[t]; }
  }
#pragma unroll
  for (int t = 0; t < 10; ++t) idx_out[(size_t)row * 10 + t] = (ushort)ri[t];
}

// ---------- u = x*W_bot ; v = x*(W_top - W_bot) + b  (W staged in LDS) ----------
// VERBATIM r0 (4 points/block). r7 lesson: 16-pt blocking was +36us/call.
__global__ __launch_bounds__(256) void uv_kernel(const float* __restrict__ Xf, int CIN,
                                                 const float* __restrict__ W,
                                                 const float* __restrict__ bias,
                                                 float* __restrict__ U, float* __restrict__ V) {
  __shared__ float Ws[8192];  // 2*CIN*64 floats, max 32KB at CIN=64
  int tid = threadIdx.x;
  int c = tid & 63, p = tid >> 6;
  int n = blockIdx.x * 4 + p;
  const int tot = CIN * 128;
  for (int i = tid; i < tot; i += 256) Ws[i] = W[i];
  __syncthreads();
  const float* xr = Xf + (size_t)n * CIN;
  float vt = 0.f, vb = 0.f;
  for (int m = 0; m < CIN; ++m) {
    float xm = xr[m];
    vt = fmaf(xm, Ws[m * 64 + c], vt);
    vb = fmaf(xm, Ws[(CIN + m) * 64 + c], vb);
  }
  U[(size_t)n * 64 + c] = vb;
  V[(size_t)n * 64 + c] = vt - vb + bias[c];
}

// ---------- BN batch stats ----------
__global__ __launch_bounds__(256) void stats_kernel(const float* __restrict__ U,
                                                    const float* __restrict__ V,
                                                    const ushort* __restrict__ idx,
                                                    float* __restrict__ accum) {
  int tid = threadIdx.x;
  int c = tid & 63, p = tid >> 6;
  int base = blockIdx.x * 64;  // 256 blocks x 64 points
  float s = 0.f, s2 = 0.f;
  for (int ch = 0; ch < 16; ++ch) {
    int n = base + ch * 4 + p;
    float vn = V[(size_t)n * 64 + c];
    const ushort* in_ = idx + (size_t)n * 10;
#pragma unroll
    for (int k = 0; k < 10; ++k) {
      float h = vn + U[(size_t)in_[k] * 64 + c];
      s += h;
      s2 = fmaf(h, h, s2);
    }
  }
  __shared__ float red[256], red2[256];
  red[tid] = s; red2[tid] = s2;
  __syncthreads();
  if (tid < 64) {
    float ts = red[tid] + red[64 + tid] + red[128 + tid] + red[192 + tid];
    float t2 = red2[tid] + red2[64 + tid] + red2[128 + tid] + red2[192 + tid];
    atomicAdd(&accum[tid], ts);
    atomicAdd(&accum[64 + tid], t2);
  }
}

__global__ void bnfin_kernel(const float* __restrict__ accum,
                             const float* __restrict__ gamma,
                             const float* __restrict__ beta,
                             float* __restrict__ scale, float* __restrict__ shift) {
  int c = threadIdx.x;  // 64
  float inv = 1.f / (float)(N * KNN);
  float mu = accum[c] * inv;
  float var = accum[64 + c] * inv - mu * mu;
  float sc = gamma[c] * rsqrtf(var + 1e-5f);
  scale[c] = sc;
  shift[c] = fmaf(-mu, sc, beta[c]);
}

// ---------- apply (BN) + ReLU + max over k, FUSED with next layer's prep ----------
// r8 WIN: prep128s eliminated; numerics identical to the standalone prep.
__global__ __launch_bounds__(256) void apply_kernel(const float* __restrict__ U,
                                                    const float* __restrict__ V,
                                                    const ushort* __restrict__ idx,
                                                    const float* __restrict__ scale,
                                                    const float* __restrict__ shift,
                                                    int use_bn,
                                                    float* __restrict__ Fout,
                                                    ushort* __restrict__ Xp,
                                                    float* __restrict__ sq,
                                                    int* __restrict__ gtauI,
                                                    float* __restrict__ accum,
                                                    int do_prep) {
  int tid = threadIdx.x;
  int c = tid & 63, p = tid >> 6;
  int n = blockIdx.x * 4 + p;
  float sc = use_bn ? scale[c] : 1.f;
  float sh = use_bn ? shift[c] : 0.f;
  float vn = V[(size_t)n * 64 + c];
  const ushort* in_ = idx + (size_t)n * 10;
  float m = 0.f;
#pragma unroll
  for (int k = 0; k < 10; ++k) {
    float h = vn + U[(size_t)in_[k] * 64 + c];
    m = fmaxf(m, fmaf(h, sc, sh));
  }
  Fout[(size_t)n * 64 + c] = m;
  if (do_prep) {
    // bf16 hi/lo split (identical ops to prep128s)
    ushort hh = bf16_rne(m);
    ushort ll = bf16_rne(m - bf16_to_f(hh));
    Xp[(size_t)n * 128 + c] = hh;
    Xp[(size_t)n * 128 + 64 + c] = ll;
    // sq: per-4-channel exact chain (channel order), then 16-group butterfly
    int base = c & ~3;
    float v0 = __shfl(m, base + 0, 64);
    float v1 = __shfl(m, base + 1, 64);
    float v2 = __shfl(m, base + 2, 64);
    float v3 = __shfl(m, base + 3, 64);
    float ps = fmaf(v0, v0, fmaf(v1, v1, fmaf(v2, v2, v3 * v3)));
#pragma unroll
    for (int mm = 4; mm <= 32; mm <<= 1) ps += __shfl_xor(ps, mm, 64);
    if (c == 0) {
      sq[n] = ps;
      gtauI[n] = 0x7F7F7F7F;
    }
    if (blockIdx.x == 0 && tid < 128) accum[tid] = 0.f;
  }
}

// ---------- segment max pooling, stage 1 (stage 2 fused into head) ----------
__global__ __launch_bounds__(256) void pool1_kernel(const float* __restrict__ f1,
                                                    const float* __restrict__ f2,
                                                    const float* __restrict__ f3,
                                                    const float* __restrict__ f4,
                                                    const int* __restrict__ n_pts,
                                                    float* __restrict__ Pp) {
  int b = blockIdx.x >> 2;
  int q = blockIdx.x & 3;
  int c = threadIdx.x;
  int off = 0;
  for (int i = 0; i < b; ++i) off += n_pts[i];
  int cnt_ = n_pts[b];
  int s0 = off + (cnt_ * q) / 4;
  int s1 = off + (cnt_ * (q + 1)) / 4;
  const float* f = (c < 64) ? f1 : (c < 128) ? f2 : (c < 192) ? f3 : f4;
  int ch = c & 63;
  float m = -3.4e38f;
  for (int t = s0; t < s1; ++t) m = fmaxf(m, f[(size_t)t * 64 + ch]);
  Pp[((size_t)q * 64 + b) * 256 + c] = m;
}

// ---------- head: 4-way pool max + tanh(P@Wp + bp) + L2 normalize ----------
__global__ __launch_bounds__(128) void head_kernel(const float* __restrict__ Pp,
                                                   const float* __restrict__ Wp,
                                                   const float* __restrict__ bp,
                                                   float* __restrict__ out) {
  int b = blockIdx.x;
  int c = threadIdx.x;
  __shared__ float ps[256];
#pragma unroll
  for (int j = 0; j < 2; ++j) {
    int cc = c + j * 128;
    float m = Pp[(size_t)b * 256 + cc];
#pragma unroll
    for (int q = 1; q < 4; ++q) m = fmaxf(m, Pp[((size_t)q * 64 + b) * 256 + cc]);
    ps[cc] = m;
  }
  __syncthreads();
  float acc = bp[c];
  for (int m = 0; m < 256; ++m) acc = fmaf(ps[m], Wp[m * 128 + c], acc);
  float t = tanhf(acc);
  __shared__ float red[128];
  red[c] = t * t;
  __syncthreads();
  for (int s = 64; s > 0; s >>= 1) {
    if (c < s) red[c] += red[c + s];
    __syncthreads();
  }
  float nrm = sqrtf(red[0]);
  out[b * 128 + c] = t / (nrm + 1e-9f);
}

extern "C" void kernel_launch(void* const* d_in, const int* in_sizes, int n_in,
                              void* d_out, int out_size, void* d_ws, size_t ws_size,
                              hipStream_t stream) {
  const float* x = (const float*)d_in[0];
  const int* n_pts = (const int*)d_in[1];
  const float* W1 = (const float*)d_in[2];
  const float* b1 = (const float*)d_in[3];
  const float* g1 = (const float*)d_in[4];
  const float* be1 = (const float*)d_in[5];
  const float* W2 = (const float*)d_in[6];
  const float* b2 = (const float*)d_in[7];
  const float* W3 = (const float*)d_in[8];
  const float* b3 = (const float*)d_in[9];
  const float* g3 = (const float*)d_in[10];
  const float* be3 = (const float*)d_in[11];
  const float* W4 = (const float*)d_in[12];
  const float* b4 = (const float*)d_in[13];
  const float* Wp = (const float*)d_in[14];
  const float* bp = (const float*)d_in[15];
  float* out = (float*)d_out;

  char* w = (char*)d_ws;
  auto alloc = [&](size_t bytes) {
    char* p = w;
    w += (bytes + 255) & ~(size_t)255;
    return p;
  };
  const size_t FS = (size_t)N * 64 * 4;
  float* f1 = (float*)alloc(FS);
  float* f2 = (float*)alloc(FS);
  float* f3 = (float*)alloc(FS);
  float* f4 = (float*)alloc(FS);
  float* Ub = (float*)alloc(FS);
  ushort* Xp128 = (ushort*)alloc((size_t)N * 128 * 2);        // 4 MB (own buffer;
                                                              // apply reads U while writing Xp)
  float* dpartf = (float*)alloc((size_t)NS64 * N * 10 * 4);   // 7.86 MB
  ushort* iparti = (ushort*)alloc((size_t)NS64 * N * 10 * 2); // 3.93 MB
  float4* xp = (float4*)alloc((size_t)N * 16);
  float* sqb = (float*)alloc((size_t)N * 4);
  int* gtauI = (int*)alloc((size_t)N * 4);
  ushort* idxb = (ushort*)alloc((size_t)N * 10 * 2);
  float* accum = (float*)alloc(512);
  float* scaleb = (float*)alloc(256);
  float* shiftb = (float*)alloc(256);
  float* Ppart = (float*)alloc((size_t)4 * 64 * 256 * 4);
  // V overlays dpart's first 4 MB: dpart consumed by merge BEFORE uv writes V;
  // V consumed by stats/apply BEFORE the next layer's knn writes dpart.
  float* Vb = dpartf;
  (void)ws_size; (void)n_in; (void)in_sizes; (void)out_size;

  auto run_layer = [&](const float* fin, int cin, const float* W, const float* b,
                       const float* g, const float* be, int use_bn, int do_prep,
                       float* fout) {
    if (cin == 3) {
      pack3_kernel<<<N / 256, 256, 0, stream>>>(fin, xp, gtauI, accum);
      knn3g_kernel<<<64 * NS3, 256, 0, stream>>>(xp, gtauI, dpartf, iparti);
      merge_kernel<NS3><<<N / 256, 256, 0, stream>>>(dpartf, iparti, idxb);
    } else {
      // Xp128/sq/gtauI already written by the PREVIOUS layer's fused apply
      knn64w_kernel<<<64 * NS64, 256, 0, stream>>>(Xp128, sqb, gtauI, dpartf, iparti);
      merge_kernel<NS64><<<N / 256, 256, 0, stream>>>(dpartf, iparti, idxb);
    }
    uv_kernel<<<N / 4, 256, 0, stream>>>(fin, cin, W, b, Ub, Vb);
    if (use_bn) {
      stats_kernel<<<256, 256, 0, stream>>>(Ub, Vb, idxb, accum);
      bnfin_kernel<<<1, 64, 0, stream>>>(accum, g, be, scaleb, shiftb);
    }
    apply_kernel<<<N / 4, 256, 0, stream>>>(Ub, Vb, idxb, scaleb, shiftb, use_bn,
                                            fout, Xp128, sqb, gtauI, accum, do_prep);
  };

  run_layer(x, 3, W1, b1, g1, be1, 1, 1, f1);
  run_layer(f1, 64, W2, b2, nullptr, nullptr, 0, 1, f2);
  run_layer(f2, 64, W3, b3, g3, be3, 1, 1, f3);
  run_layer(f3, 64, W4, b4, nullptr, nullptr, 0, 0, f4);
  pool1_kernel<<<256, 256, 0, stream>>>(f1, f2, f3, f4, n_pts, Ppart);
  head_kernel<<<64, 128, 0, stream>>>(Ppart, Wp, bp, out);
}

// Round 11
// 1130.657 us; speedup vs baseline: 1.0996x; 1.0996x over previous
//
#include <hip/hip_runtime.h>
#include <hip/hip_bf16.h>

constexpr int N = 16384;   // points
constexpr int KNN = 10;
constexpr int CF = 64;     // feature channels per edgeconv
constexpr int NS64 = 12;   // col splits for knn64 (grid 64*12 = 768 = 3 blocks/CU)
constexpr int NS3 = 12;    // col splits for knn3  (grid 64*12 = 768)

#define FBIG 1e30f

typedef __attribute__((ext_vector_type(8))) __bf16 bfv8;
typedef __attribute__((ext_vector_type(4))) float f32x4;

// ---------- top-k insert (replace-max) ----------
#define TOPK_INSERT(dval, jval)                                            \
  if ((dval) < bmax) {                                                     \
    float mv = bd[0]; int slot = 0;                                        \
    _Pragma("unroll") for (int s_ = 1; s_ < 10; ++s_)                      \
      if (bd[s_] > mv) { mv = bd[s_]; slot = s_; }                         \
    _Pragma("unroll") for (int s_ = 0; s_ < 10; ++s_)                      \
      if (slot == s_) { bd[s_] = (dval); bi[s_] = (jval); }                \
    bmax = bd[0];                                                          \
    _Pragma("unroll") for (int s_ = 1; s_ < 10; ++s_)                      \
      bmax = fmaxf(bmax, bd[s_]);                                          \
  }

__device__ inline ushort bf16_rne(float x) {
  unsigned u = __float_as_uint(x);
  return (ushort)((u + 0x7FFFu + ((u >> 16) & 1u)) >> 16);
}
__device__ inline float bf16_to_f(ushort h) { return __uint_as_float(((unsigned)h) << 16); }

// ---------- pack x (3ch) into float4 with sq norm; init gtau + accum ----------
__global__ __launch_bounds__(256) void pack3_kernel(const float* __restrict__ X,
                                                    float4* __restrict__ xp,
                                                    int* __restrict__ gtauI,
                                                    float* __restrict__ accum) {
  int i = blockIdx.x * 256 + threadIdx.x;
  float x0 = X[3 * i], x1 = X[3 * i + 1], x2 = X[3 * i + 2];
  float s = fmaf(x0, x0, fmaf(x1, x1, x2 * x2));
  xp[i] = make_float4(x0, x1, x2, s);
  gtauI[i] = 0x7F7F7F7F;  // ~3.39e38
  if (blockIdx.x == 0 && threadIdx.x < 128) accum[threadIdx.x] = 0.f;
}

// ---------- kNN for C=64 via bf16-split MFMA: 32-col chunks (r13-banked, 213us) ----------
// r0-VERBATIM structure + r9 s_setprio bracket around MFMA clusters (T5, -3.5us/call).
// Session ledger:
//  r14: __launch_bounds__(256,4) caps 64 VGPR -> pinned A-frags demoted, A
//       re-streamed from global (FETCH 34MB->1.37GB, 765us). Keep (256,3).
//  r1:  folding sq into MFMA via meta-fragment (384B rows) -> dependent-chain +
//       stream-pattern break, 308us. Keep 256B rows + zero-seeded acc.
//  r2:  acc seeded with -0.5*sq_j + thr-compare -> load on MFMA critical path,
//       297us. Keep epilogue fmaf(-2,acc,sqi+sj).
//  r3:  per-lane register top-k (swapped operands) -> 4x column traffic + exec-
//       unioned insert storms, 667us. Keep batch LDS buffer + drain.
//  r5:  half-chunk drains (cap 17, NS=16) -> 2x drain/barrier fixed cost, 281us.
//       Keep single drain per 32-col chunk, capacity 33, NS=12.
//  r6:  streaming-insert merge (1-wave blocks) -> serial dep chain, +46us total.
//  r7:  uv 16-pt blocking -> +36us/call. Keep 4-pt uv.
//  r8:  prep128s fused into apply (bit-identical) -> -23us. WIN.
//  r9:  s_setprio around MFMA cluster -> -10us total. WIN. (absmax tie-flips
//       between 0.0009155/0.0015869: gtau race timing resolves (d,id) boundary
//       ties differently; both valid & passing.)
//  r10: hierarchical register merge -> +53us (serial group phases). Keep FLAT
//       merge (spilled scratch re-scan pipelines fine).
__global__ __launch_bounds__(256, 3) void knn64w_kernel(const ushort* __restrict__ Xp,
                                                        const float* __restrict__ sq,
                                                        int* __restrict__ gtauI,
                                                        float* __restrict__ dpart,
                                                        ushort* __restrict__ ipart) {
  __shared__ float bufD[4][64 * 33];
  __shared__ ushort bufI[4][64 * 34];
  __shared__ __align__(16) float tauS[4][64];
  __shared__ int cntS[4][64];

  const int tid = threadIdx.x;
  const int w = tid >> 6, l = tid & 63, lp = l & 15, g = l >> 4;
  const int rg = blockIdx.x / NS64, cs = blockIdx.x % NS64;
  const int wbase = rg * 256 + w * 64;
  const int myrow = wbase + l;
  const int c0 = (512 * cs) / NS64, c1 = (512 * (cs + 1)) / NS64;  // 32-col chunks

  tauS[w][l] = FBIG;
  cntS[w][l] = 0;
  __builtin_amdgcn_wave_barrier();

  // A fragments: 4 row-tiles (rows wbase + rt*16 + lp, k-slice g*8)
  bfv8 aH1[4], aH2[4], aL1[4], aL2[4];
#pragma unroll
  for (int rt = 0; rt < 4; ++rt) {
    const size_t ao = (size_t)(wbase + rt * 16 + lp) * 128 + g * 8;
    aH1[rt] = *(const bfv8*)&Xp[ao];
    aH2[rt] = *(const bfv8*)&Xp[ao + 32];
    aL1[rt] = *(const bfv8*)&Xp[ao + 64];
    aL2[rt] = *(const bfv8*)&Xp[ao + 96];
  }
  float sqi[16];
#pragma unroll
  for (int rt = 0; rt < 4; ++rt)
#pragma unroll
    for (int r = 0; r < 4; ++r) sqi[rt * 4 + r] = sq[wbase + rt * 16 + g * 4 + r];

  float bd[10]; int bi[10]; float bmax = FBIG; float lastPub = FBIG;
#pragma unroll
  for (int s = 0; s < 10; ++s) { bd[s] = FBIG; bi[s] = 0x7fffffff; }
  int gt = 0x7F7F7F7F;

  for (int t = c0; t < c1; ++t) {
    const int col0 = t * 32 + lp;
    const int col1 = col0 + 16;
    const size_t bo0 = (size_t)col0 * 128 + g * 8;
    bfv8 p0 = *(const bfv8*)&Xp[bo0];
    bfv8 p1 = *(const bfv8*)&Xp[bo0 + 32];
    bfv8 p2 = *(const bfv8*)&Xp[bo0 + 64];
    bfv8 p3 = *(const bfv8*)&Xp[bo0 + 96];
    const size_t bo1 = (size_t)col1 * 128 + g * 8;
    bfv8 q0 = *(const bfv8*)&Xp[bo1];
    bfv8 q1 = *(const bfv8*)&Xp[bo1 + 32];
    bfv8 q2 = *(const bfv8*)&Xp[bo1 + 64];
    bfv8 q3 = *(const bfv8*)&Xp[bo1 + 96];
    float sj0 = sq[col0];
    float sj1 = sq[col1];
    int gtn = gtauI[myrow];

    __builtin_amdgcn_wave_barrier();
    {  // drain prev chunk: every lane owns row l   (prio 0: VALU/LDS phase)
      const int c = cntS[w][l];
      if (c) {
        const float* bD = &bufD[w][l * 33];
        const ushort* bI = &bufI[w][l * 34];
#pragma unroll 1
        for (int j = 0; j < c; ++j) {
          float d = bD[j];
          int ii = (int)bI[j];
          TOPK_INSERT(d, ii);
        }
        cntS[w][l] = 0;
      }
      tauS[w][l] = fminf(bmax, __int_as_float(gt));
      if (bmax < lastPub) {  // publish only on improvement
        atomicMin(&gtauI[myrow], __float_as_int(bmax));
        lastPub = bmax;
      }
    }
    __builtin_amdgcn_wave_barrier();
    gt = gtn;

#pragma unroll
    for (int rt = 0; rt < 4; ++rt) {
      f32x4 taur = *(const f32x4*)&tauS[w][rt * 16 + g * 4];
      __builtin_amdgcn_s_setprio(1);  // MFMA cluster: favor this wave's issue
      f32x4 acc0 = {0.f, 0.f, 0.f, 0.f};
      acc0 = __builtin_amdgcn_mfma_f32_16x16x32_bf16(aH1[rt], p0, acc0, 0, 0, 0);
      acc0 = __builtin_amdgcn_mfma_f32_16x16x32_bf16(aH2[rt], p1, acc0, 0, 0, 0);
      acc0 = __builtin_amdgcn_mfma_f32_16x16x32_bf16(aH1[rt], p2, acc0, 0, 0, 0);
      acc0 = __builtin_amdgcn_mfma_f32_16x16x32_bf16(aH2[rt], p3, acc0, 0, 0, 0);
      acc0 = __builtin_amdgcn_mfma_f32_16x16x32_bf16(aL1[rt], p0, acc0, 0, 0, 0);
      acc0 = __builtin_amdgcn_mfma_f32_16x16x32_bf16(aL2[rt], p1, acc0, 0, 0, 0);
      f32x4 acc1 = {0.f, 0.f, 0.f, 0.f};
      acc1 = __builtin_amdgcn_mfma_f32_16x16x32_bf16(aH1[rt], q0, acc1, 0, 0, 0);
      acc1 = __builtin_amdgcn_mfma_f32_16x16x32_bf16(aH2[rt], q1, acc1, 0, 0, 0);
      acc1 = __builtin_amdgcn_mfma_f32_16x16x32_bf16(aH1[rt], q2, acc1, 0, 0, 0);
      acc1 = __builtin_amdgcn_mfma_f32_16x16x32_bf16(aH2[rt], q3, acc1, 0, 0, 0);
      acc1 = __builtin_amdgcn_mfma_f32_16x16x32_bf16(aL1[rt], q0, acc1, 0, 0, 0);
      acc1 = __builtin_amdgcn_mfma_f32_16x16x32_bf16(aL2[rt], q1, acc1, 0, 0, 0);
      __builtin_amdgcn_s_setprio(0);  // epilogue/insert storm: yield issue
#pragma unroll
      for (int r = 0; r < 4; ++r) {
        const int rloc = rt * 16 + g * 4 + r;
        float d0 = fmaf(-2.f, acc0[r], sqi[rt * 4 + r] + sj0);
        if (d0 < taur[r]) {
          int pos = atomicAdd(&cntS[w][rloc], 1);
          bufD[w][rloc * 33 + pos] = d0;
          bufI[w][rloc * 34 + pos] = (ushort)col0;
        }
        float d1 = fmaf(-2.f, acc1[r], sqi[rt * 4 + r] + sj1);
        if (d1 < taur[r]) {
          int pos = atomicAdd(&cntS[w][rloc], 1);
          bufD[w][rloc * 33 + pos] = d1;
          bufI[w][rloc * 34 + pos] = (ushort)col1;
        }
      }
    }
  }

  __builtin_amdgcn_wave_barrier();
  {  // final drain
    const int c = cntS[w][l];
    const float* bD = &bufD[w][l * 33];
    const ushort* bI = &bufI[w][l * 34];
#pragma unroll 1
    for (int j = 0; j < c; ++j) {
      float d = bD[j];
      int ii = (int)bI[j];
      TOPK_INSERT(d, ii);
    }
  }
  float* dp = dpart + ((size_t)cs * N + myrow) * 10;
  ushort* ip = ipart + ((size_t)cs * N + myrow) * 10;
#pragma unroll
  for (int s = 0; s < 10; ++s) { dp[s] = bd[s]; ip[s] = (ushort)bi[s]; }
}

// ---------- kNN for C=3, exact fp32 (cancellation-sensitive: keep fp32!) ----------
// VERBATIM r0 structure: 32-col chunks, single drain, capacity 33.
__global__ __launch_bounds__(256, 3) void knn3g_kernel(const float4* __restrict__ xp,
                                                       int* __restrict__ gtauI,
                                                       float* __restrict__ dpart,
                                                       ushort* __restrict__ ipart) {
  __shared__ float bufD[4][64 * 33];
  __shared__ ushort bufI[4][64 * 34];
  __shared__ __align__(16) float tauS[4][64];
  __shared__ int cntS[4][64];

  const int tid = threadIdx.x;
  const int w = tid >> 6, l = tid & 63, lp = l & 15, g = l >> 4;
  const int rg = blockIdx.x / NS3, cs = blockIdx.x % NS3;
  const int wbase = rg * 256 + w * 64;
  const int myrow = wbase + l;
  const int c0 = (512 * cs) / NS3, c1 = (512 * (cs + 1)) / NS3;  // 32-col chunks

  tauS[w][l] = FBIG;
  cntS[w][l] = 0;
  __builtin_amdgcn_wave_barrier();

  float4 rw[16];
#pragma unroll
  for (int rt = 0; rt < 4; ++rt)
#pragma unroll
    for (int r = 0; r < 4; ++r) rw[rt * 4 + r] = xp[wbase + rt * 16 + g * 4 + r];

  float bd[10]; int bi[10]; float bmax = FBIG; float lastPub = FBIG;
#pragma unroll
  for (int s = 0; s < 10; ++s) { bd[s] = FBIG; bi[s] = 0x7fffffff; }
  int gt = 0x7F7F7F7F;

  for (int t = c0; t < c1; ++t) {
    const int col0 = t * 32 + lp;
    const int col1 = col0 + 16;
    const float4 oc0 = xp[col0];
    const float4 oc1 = xp[col1];
    int gtn = gtauI[myrow];

    __builtin_amdgcn_wave_barrier();
    {  // drain prev chunk
      const int c = cntS[w][l];
      if (c) {
        const float* bD = &bufD[w][l * 33];
        const ushort* bI = &bufI[w][l * 34];
#pragma unroll 1
        for (int j = 0; j < c; ++j) {
          float d = bD[j];
          int ii = (int)bI[j];
          TOPK_INSERT(d, ii);
        }
        cntS[w][l] = 0;
      }
      tauS[w][l] = fminf(bmax, __int_as_float(gt));
      if (bmax < lastPub) {
        atomicMin(&gtauI[myrow], __float_as_int(bmax));
        lastPub = bmax;
      }
    }
    __builtin_amdgcn_wave_barrier();
    gt = gtn;

#pragma unroll
    for (int rt = 0; rt < 4; ++rt) {
      f32x4 taur = *(const f32x4*)&tauS[w][rt * 16 + g * 4];
#pragma unroll
      for (int r = 0; r < 4; ++r) {
        const float4 m = rw[rt * 4 + r];
        const int rloc = rt * 16 + g * 4 + r;
        float dot0 = fmaf(m.x, oc0.x, fmaf(m.y, oc0.y, m.z * oc0.z));
        float d0 = fmaf(-2.f, dot0, m.w + oc0.w);  // same chain as validated knn3
        if (d0 < taur[r]) {
          int pos = atomicAdd(&cntS[w][rloc], 1);
          bufD[w][rloc * 33 + pos] = d0;
          bufI[w][rloc * 34 + pos] = (ushort)col0;
        }
        float dot1 = fmaf(m.x, oc1.x, fmaf(m.y, oc1.y, m.z * oc1.z));
        float d1 = fmaf(-2.f, dot1, m.w + oc1.w);
        if (d1 < taur[r]) {
          int pos = atomicAdd(&cntS[w][rloc], 1);
          bufD[w][rloc * 33 + pos] = d1;
          bufI[w][rloc * 34 + pos] = (ushort)col1;
        }
      }
    }
  }

  __builtin_amdgcn_wave_barrier();
  {  // final drain
    const int c = cntS[w][l];
    const float* bD = &bufD[w][l * 33];
    const ushort* bI = &bufI[w][l * 34];
#pragma unroll 1
    for (int j = 0; j < c; ++j) {
      float d = bD[j];
      int ii = (int)bI[j];
      TOPK_INSERT(d, ii);
    }
  }
  float* dp = dpart + ((size_t)cs * N + myrow) * 10;
  ushort* ip = ipart + ((size_t)cs * N + myrow) * 10;
#pragma unroll
  for (int s = 0; s < 10; ++s) { dp[s] = bd[s]; ip[s] = (ushort)bi[s]; }
}

// ---------- FUSED: merge (64 blocks, flat r0 body) ∥ uv (4096 blocks, r0 body) ----------
// r11: merge and uv are mutually independent (merge: dpart->idxb; uv: fin,W->U,V).
// One launch, block-partitioned: merge blocks first (latency-bound, start early),
// then uv blocks. Both bodies VERBATIM from their measured-good standalone forms
// (r10 lesson: flat merge beats register-hierarchical; r7 lesson: 4-pt uv).
// Requires V un-overlaid from dpart (merge reads dpart while uv writes V).
template <int S>
__global__ __launch_bounds__(256) void mergeuv_kernel(const float* __restrict__ dpart,
                                                      const ushort* __restrict__ ipart,
                                                      ushort* __restrict__ idx_out,
                                                      const float* __restrict__ Xf, int CIN,
                                                      const float* __restrict__ W,
                                                      const float* __restrict__ bias,
                                                      float* __restrict__ U,
                                                      float* __restrict__ V) {
  __shared__ float Ws[8192];  // used by uv branch only (2*CIN*64 floats, max 32KB)
  if (blockIdx.x < N / 256) {
    // ---- merge branch: flat r0 body ----
    const int row = blockIdx.x * 256 + threadIdx.x;
    float d[S * 10]; int id_[S * 10];
#pragma unroll
    for (int p = 0; p < S; ++p)
#pragma unroll
      for (int s = 0; s < 10; ++s) {
        d[p * 10 + s] = dpart[((size_t)p * N + row) * 10 + s];
        id_[p * 10 + s] = (int)ipart[((size_t)p * N + row) * 10 + s];
      }
#pragma unroll
    for (int t = 0; t < 10; ++t) {
      float dm = d[0]; int im = id_[0]; int slot = 0;
#pragma unroll
      for (int e = 1; e < S * 10; ++e) {
        bool better = (d[e] < dm) || (d[e] == dm && id_[e] < im);
        if (better) { dm = d[e]; im = id_[e]; slot = e; }
      }
      idx_out[(size_t)row * 10 + t] = (ushort)im;
#pragma unroll
      for (int e = 0; e < S * 10; ++e)
        if (e == slot) d[e] = FBIG;
    }
  } else {
    // ---- uv branch: r0 body (4 points/block) ----
    const int bb = blockIdx.x - N / 256;
    int tid = threadIdx.x;
    int c = tid & 63, p = tid >> 6;
    int n = bb * 4 + p;
    const int tot = CIN * 128;
    for (int i = tid; i < tot; i += 256) Ws[i] = W[i];
    __syncthreads();
    const float* xr = Xf + (size_t)n * CIN;
    float vt = 0.f, vb = 0.f;
    for (int m = 0; m < CIN; ++m) {
      float xm = xr[m];
      vt = fmaf(xm, Ws[m * 64 + c], vt);
      vb = fmaf(xm, Ws[(CIN + m) * 64 + c], vb);
    }
    U[(size_t)n * 64 + c] = vb;
    V[(size_t)n * 64 + c] = vt - vb + bias[c];
  }
}

// ---------- BN batch stats ----------
__global__ __launch_bounds__(256) void stats_kernel(const float* __restrict__ U,
                                                    const float* __restrict__ V,
                                                    const ushort* __restrict__ idx,
                                                    float* __restrict__ accum) {
  int tid = threadIdx.x;
  int c = tid & 63, p = tid >> 6;
  int base = blockIdx.x * 64;  // 256 blocks x 64 points
  float s = 0.f, s2 = 0.f;
  for (int ch = 0; ch < 16; ++ch) {
    int n = base + ch * 4 + p;
    float vn = V[(size_t)n * 64 + c];
    const ushort* in_ = idx + (size_t)n * 10;
#pragma unroll
    for (int k = 0; k < 10; ++k) {
      float h = vn + U[(size_t)in_[k] * 64 + c];
      s += h;
      s2 = fmaf(h, h, s2);
    }
  }
  __shared__ float red[256], red2[256];
  red[tid] = s; red2[tid] = s2;
  __syncthreads();
  if (tid < 64) {
    float ts = red[tid] + red[64 + tid] + red[128 + tid] + red[192 + tid];
    float t2 = red2[tid] + red2[64 + tid] + red2[128 + tid] + red2[192 + tid];
    atomicAdd(&accum[tid], ts);
    atomicAdd(&accum[64 + tid], t2);
  }
}

__global__ void bnfin_kernel(const float* __restrict__ accum,
                             const float* __restrict__ gamma,
                             const float* __restrict__ beta,
                             float* __restrict__ scale, float* __restrict__ shift) {
  int c = threadIdx.x;  // 64
  float inv = 1.f / (float)(N * KNN);
  float mu = accum[c] * inv;
  float var = accum[64 + c] * inv - mu * mu;
  float sc = gamma[c] * rsqrtf(var + 1e-5f);
  scale[c] = sc;
  shift[c] = fmaf(-mu, sc, beta[c]);
}

// ---------- apply (BN) + ReLU + max over k, FUSED with next layer's prep ----------
// r8 WIN: prep128s eliminated; numerics identical to the standalone prep.
__global__ __launch_bounds__(256) void apply_kernel(const float* __restrict__ U,
                                                    const float* __restrict__ V,
                                                    const ushort* __restrict__ idx,
                                                    const float* __restrict__ scale,
                                                    const float* __restrict__ shift,
                                                    int use_bn,
                                                    float* __restrict__ Fout,
                                                    ushort* __restrict__ Xp,
                                                    float* __restrict__ sq,
                                                    int* __restrict__ gtauI,
                                                    float* __restrict__ accum,
                                                    int do_prep) {
  int tid = threadIdx.x;
  int c = tid & 63, p = tid >> 6;
  int n = blockIdx.x * 4 + p;
  float sc = use_bn ? scale[c] : 1.f;
  float sh = use_bn ? shift[c] : 0.f;
  float vn = V[(size_t)n * 64 + c];
  const ushort* in_ = idx + (size_t)n * 10;
  float m = 0.f;
#pragma unroll
  for (int k = 0; k < 10; ++k) {
    float h = vn + U[(size_t)in_[k] * 64 + c];
    m = fmaxf(m, fmaf(h, sc, sh));
  }
  Fout[(size_t)n * 64 + c] = m;
  if (do_prep) {
    // bf16 hi/lo split (identical ops to prep128s)
    ushort hh = bf16_rne(m);
    ushort ll = bf16_rne(m - bf16_to_f(hh));
    Xp[(size_t)n * 128 + c] = hh;
    Xp[(size_t)n * 128 + 64 + c] = ll;
    // sq: per-4-channel exact chain (channel order), then 16-group butterfly
    int base = c & ~3;
    float v0 = __shfl(m, base + 0, 64);
    float v1 = __shfl(m, base + 1, 64);
    float v2 = __shfl(m, base + 2, 64);
    float v3 = __shfl(m, base + 3, 64);
    float ps = fmaf(v0, v0, fmaf(v1, v1, fmaf(v2, v2, v3 * v3)));
#pragma unroll
    for (int mm = 4; mm <= 32; mm <<= 1) ps += __shfl_xor(ps, mm, 64);
    if (c == 0) {
      sq[n] = ps;
      gtauI[n] = 0x7F7F7F7F;
    }
    if (blockIdx.x == 0 && tid < 128) accum[tid] = 0.f;
  }
}

// ---------- segment max pooling, stage 1 (stage 2 fused into head) ----------
__global__ __launch_bounds__(256) void pool1_kernel(const float* __restrict__ f1,
                                                    const float* __restrict__ f2,
                                                    const float* __restrict__ f3,
                                                    const float* __restrict__ f4,
                                                    const int* __restrict__ n_pts,
                                                    float* __restrict__ Pp) {
  int b = blockIdx.x >> 2;
  int q = blockIdx.x & 3;
  int c = threadIdx.x;
  int off = 0;
  for (int i = 0; i < b; ++i) off += n_pts[i];
  int cnt_ = n_pts[b];
  int s0 = off + (cnt_ * q) / 4;
  int s1 = off + (cnt_ * (q + 1)) / 4;
  const float* f = (c < 64) ? f1 : (c < 128) ? f2 : (c < 192) ? f3 : f4;
  int ch = c & 63;
  float m = -3.4e38f;
  for (int t = s0; t < s1; ++t) m = fmaxf(m, f[(size_t)t * 64 + ch]);
  Pp[((size_t)q * 64 + b) * 256 + c] = m;
}

// ---------- head: 4-way pool max + tanh(P@Wp + bp) + L2 normalize ----------
__global__ __launch_bounds__(128) void head_kernel(const float* __restrict__ Pp,
                                                   const float* __restrict__ Wp,
                                                   const float* __restrict__ bp,
                                                   float* __restrict__ out) {
  int b = blockIdx.x;
  int c = threadIdx.x;
  __shared__ float ps[256];
#pragma unroll
  for (int j = 0; j < 2; ++j) {
    int cc = c + j * 128;
    float m = Pp[(size_t)b * 256 + cc];
#pragma unroll
    for (int q = 1; q < 4; ++q) m = fmaxf(m, Pp[((size_t)q * 64 + b) * 256 + cc]);
    ps[cc] = m;
  }
  __syncthreads();
  float acc = bp[c];
  for (int m = 0; m < 256; ++m) acc = fmaf(ps[m], Wp[m * 128 + c], acc);
  float t = tanhf(acc);
  __shared__ float red[128];
  red[c] = t * t;
  __syncthreads();
  for (int s = 64; s > 0; s >>= 1) {
    if (c < s) red[c] += red[c + s];
    __syncthreads();
  }
  float nrm = sqrtf(red[0]);
  out[b * 128 + c] = t / (nrm + 1e-9f);
}

extern "C" void kernel_launch(void* const* d_in, const int* in_sizes, int n_in,
                              void* d_out, int out_size, void* d_ws, size_t ws_size,
                              hipStream_t stream) {
  const float* x = (const float*)d_in[0];
  const int* n_pts = (const int*)d_in[1];
  const float* W1 = (const float*)d_in[2];
  const float* b1 = (const float*)d_in[3];
  const float* g1 = (const float*)d_in[4];
  const float* be1 = (const float*)d_in[5];
  const float* W2 = (const float*)d_in[6];
  const float* b2 = (const float*)d_in[7];
  const float* W3 = (const float*)d_in[8];
  const float* b3 = (const float*)d_in[9];
  const float* g3 = (const float*)d_in[10];
  const float* be3 = (const float*)d_in[11];
  const float* W4 = (const float*)d_in[12];
  const float* b4 = (const float*)d_in[13];
  const float* Wp = (const float*)d_in[14];
  const float* bp = (const float*)d_in[15];
  float* out = (float*)d_out;

  char* w = (char*)d_ws;
  auto alloc = [&](size_t bytes) {
    char* p = w;
    w += (bytes + 255) & ~(size_t)255;
    return p;
  };
  const size_t FS = (size_t)N * 64 * 4;
  float* f1 = (float*)alloc(FS);
  float* f2 = (float*)alloc(FS);
  float* f3 = (float*)alloc(FS);
  float* f4 = (float*)alloc(FS);
  float* Ub = (float*)alloc(FS);
  float* Vb = (float*)alloc(FS);                              // r11: own buffer —
                                                              // merge reads dpart WHILE uv writes V
  ushort* Xp128 = (ushort*)alloc((size_t)N * 128 * 2);        // 4 MB (own buffer;
                                                              // apply reads U while writing Xp)
  float* dpartf = (float*)alloc((size_t)NS64 * N * 10 * 4);   // 7.86 MB
  ushort* iparti = (ushort*)alloc((size_t)NS64 * N * 10 * 2); // 3.93 MB
  float4* xp = (float4*)alloc((size_t)N * 16);
  float* sqb = (float*)alloc((size_t)N * 4);
  int* gtauI = (int*)alloc((size_t)N * 4);
  ushort* idxb = (ushort*)alloc((size_t)N * 10 * 2);
  float* accum = (float*)alloc(512);
  float* scaleb = (float*)alloc(256);
  float* shiftb = (float*)alloc(256);
  float* Ppart = (float*)alloc((size_t)4 * 64 * 256 * 4);
  (void)ws_size; (void)n_in; (void)in_sizes; (void)out_size;

  auto run_layer = [&](const float* fin, int cin, const float* W, const float* b,
                       const float* g, const float* be, int use_bn, int do_prep,
                       float* fout) {
    if (cin == 3) {
      pack3_kernel<<<N / 256, 256, 0, stream>>>(fin, xp, gtauI, accum);
      knn3g_kernel<<<64 * NS3, 256, 0, stream>>>(xp, gtauI, dpartf, iparti);
      mergeuv_kernel<NS3><<<N / 256 + N / 4, 256, 0, stream>>>(dpartf, iparti, idxb,
                                                               fin, cin, W, b, Ub, Vb);
    } else {
      // Xp128/sq/gtauI already written by the PREVIOUS layer's fused apply
      knn64w_kernel<<<64 * NS64, 256, 0, stream>>>(Xp128, sqb, gtauI, dpartf, iparti);
      mergeuv_kernel<NS64><<<N / 256 + N / 4, 256, 0, stream>>>(dpartf, iparti, idxb,
                                                                fin, cin, W, b, Ub, Vb);
    }
    if (use_bn) {
      stats_kernel<<<256, 256, 0, stream>>>(Ub, Vb, idxb, accum);
      bnfin_kernel<<<1, 64, 0, stream>>>(accum, g, be, scaleb, shiftb);
    }
    apply_kernel<<<N / 4, 256, 0, stream>>>(Ub, Vb, idxb, scaleb, shiftb, use_bn,
                                            fout, Xp128, sqb, gtauI, accum, do_prep);
  };

  run_layer(x, 3, W1, b1, g1, be1, 1, 1, f1);
  run_layer(f1, 64, W2, b2, nullptr, nullptr, 0, 1, f2);
  run_layer(f2, 64, W3, b3, g3, be3, 1, 1, f3);
  run_layer(f3, 64, W4, b4, nullptr, nullptr, 0, 0, f4);
  pool1_kernel<<<256, 256, 0, stream>>>(f1, f2, f3, f4, n_pts, Ppart);
  head_kernel<<<64, 128, 0, stream>>>(Ppart, Wp, bp, out);
}

// Round 12
// 1124.114 us; speedup vs baseline: 1.1060x; 1.0058x over previous
//
#include <hip/hip_runtime.h>
#include <hip/hip_bf16.h>

constexpr int N = 16384;   // points
constexpr int KNN = 10;
constexpr int CF = 64;     // feature channels per edgeconv
constexpr int NS64 = 12;   // col splits for knn64 (grid 64*12 = 768 = 3 blocks/CU)
constexpr int NS3 = 12;    // col splits for knn3  (grid 64*12 = 768)

#define FBIG 1e30f

typedef __attribute__((ext_vector_type(8))) __bf16 bfv8;
typedef __attribute__((ext_vector_type(4))) float f32x4;

// ---------- top-k insert (replace-max) ----------
#define TOPK_INSERT(dval, jval)                                            \
  if ((dval) < bmax) {                                                     \
    float mv = bd[0]; int slot = 0;                                        \
    _Pragma("unroll") for (int s_ = 1; s_ < 10; ++s_)                      \
      if (bd[s_] > mv) { mv = bd[s_]; slot = s_; }                         \
    _Pragma("unroll") for (int s_ = 0; s_ < 10; ++s_)                      \
      if (slot == s_) { bd[s_] = (dval); bi[s_] = (jval); }                \
    bmax = bd[0];                                                          \
    _Pragma("unroll") for (int s_ = 1; s_ < 10; ++s_)                      \
      bmax = fmaxf(bmax, bd[s_]);                                          \
  }

__device__ inline ushort bf16_rne(float x) {
  unsigned u = __float_as_uint(x);
  return (ushort)((u + 0x7FFFu + ((u >> 16) & 1u)) >> 16);
}
__device__ inline float bf16_to_f(ushort h) { return __uint_as_float(((unsigned)h) << 16); }

// ---------- pack x (3ch) into float4 with sq norm; init gtau + accum ----------
__global__ __launch_bounds__(256) void pack3_kernel(const float* __restrict__ X,
                                                    float4* __restrict__ xp,
                                                    int* __restrict__ gtauI,
                                                    float* __restrict__ accum) {
  int i = blockIdx.x * 256 + threadIdx.x;
  float x0 = X[3 * i], x1 = X[3 * i + 1], x2 = X[3 * i + 2];
  float s = fmaf(x0, x0, fmaf(x1, x1, x2 * x2));
  xp[i] = make_float4(x0, x1, x2, s);
  gtauI[i] = 0x7F7F7F7F;  // ~3.39e38
  if (blockIdx.x == 0 && threadIdx.x < 132) accum[threadIdx.x] = 0.f;  // incl. ticket
}

// ---------- kNN for C=64 via bf16-split MFMA: 32-col chunks (r13-banked, 213us) ----------
// r0-VERBATIM structure + r9 s_setprio bracket around MFMA clusters (T5, -3.5us/call).
// Session ledger:
//  r14: __launch_bounds__(256,4) caps 64 VGPR -> pinned A-frags demoted, A
//       re-streamed from global (FETCH 34MB->1.37GB, 765us). Keep (256,3).
//  r1:  folding sq into MFMA via meta-fragment (384B rows) -> dependent-chain +
//       stream-pattern break, 308us. Keep 256B rows + zero-seeded acc.
//  r2:  acc seeded with -0.5*sq_j + thr-compare -> load on MFMA critical path,
//       297us. Keep epilogue fmaf(-2,acc,sqi+sj).
//  r3:  per-lane register top-k (swapped operands) -> 4x column traffic + exec-
//       unioned insert storms, 667us. Keep batch LDS buffer + drain.
//  r5:  half-chunk drains (cap 17, NS=16) -> 2x drain/barrier fixed cost, 281us.
//       Keep single drain per 32-col chunk, capacity 33, NS=12.
//  r6:  streaming-insert merge (1-wave blocks) -> serial dep chain, +46us total.
//  r7:  uv 16-pt blocking -> +36us/call. Keep 4-pt uv.
//  r8:  prep128s fused into apply (bit-identical) -> -23us. WIN.
//  r9:  s_setprio around MFMA cluster -> -10us. WIN. (absmax tie-flips between
//       0.0009155/0.0015869: gtau race timing resolves boundary ties; both pass.)
//  r10: hierarchical register merge -> +53us (serial group phases). Keep FLAT merge.
//  r11: merge∥uv block-partition fusion -> -59us. WIN (launch removal + overlap).
__global__ __launch_bounds__(256, 3) void knn64w_kernel(const ushort* __restrict__ Xp,
                                                        const float* __restrict__ sq,
                                                        int* __restrict__ gtauI,
                                                        float* __restrict__ dpart,
                                                        ushort* __restrict__ ipart) {
  __shared__ float bufD[4][64 * 33];
  __shared__ ushort bufI[4][64 * 34];
  __shared__ __align__(16) float tauS[4][64];
  __shared__ int cntS[4][64];

  const int tid = threadIdx.x;
  const int w = tid >> 6, l = tid & 63, lp = l & 15, g = l >> 4;
  const int rg = blockIdx.x / NS64, cs = blockIdx.x % NS64;
  const int wbase = rg * 256 + w * 64;
  const int myrow = wbase + l;
  const int c0 = (512 * cs) / NS64, c1 = (512 * (cs + 1)) / NS64;  // 32-col chunks

  tauS[w][l] = FBIG;
  cntS[w][l] = 0;
  __builtin_amdgcn_wave_barrier();

  // A fragments: 4 row-tiles (rows wbase + rt*16 + lp, k-slice g*8)
  bfv8 aH1[4], aH2[4], aL1[4], aL2[4];
#pragma unroll
  for (int rt = 0; rt < 4; ++rt) {
    const size_t ao = (size_t)(wbase + rt * 16 + lp) * 128 + g * 8;
    aH1[rt] = *(const bfv8*)&Xp[ao];
    aH2[rt] = *(const bfv8*)&Xp[ao + 32];
    aL1[rt] = *(const bfv8*)&Xp[ao + 64];
    aL2[rt] = *(const bfv8*)&Xp[ao + 96];
  }
  float sqi[16];
#pragma unroll
  for (int rt = 0; rt < 4; ++rt)
#pragma unroll
    for (int r = 0; r < 4; ++r) sqi[rt * 4 + r] = sq[wbase + rt * 16 + g * 4 + r];

  float bd[10]; int bi[10]; float bmax = FBIG; float lastPub = FBIG;
#pragma unroll
  for (int s = 0; s < 10; ++s) { bd[s] = FBIG; bi[s] = 0x7fffffff; }
  int gt = 0x7F7F7F7F;

  for (int t = c0; t < c1; ++t) {
    const int col0 = t * 32 + lp;
    const int col1 = col0 + 16;
    const size_t bo0 = (size_t)col0 * 128 + g * 8;
    bfv8 p0 = *(const bfv8*)&Xp[bo0];
    bfv8 p1 = *(const bfv8*)&Xp[bo0 + 32];
    bfv8 p2 = *(const bfv8*)&Xp[bo0 + 64];
    bfv8 p3 = *(const bfv8*)&Xp[bo0 + 96];
    const size_t bo1 = (size_t)col1 * 128 + g * 8;
    bfv8 q0 = *(const bfv8*)&Xp[bo1];
    bfv8 q1 = *(const bfv8*)&Xp[bo1 + 32];
    bfv8 q2 = *(const bfv8*)&Xp[bo1 + 64];
    bfv8 q3 = *(const bfv8*)&Xp[bo1 + 96];
    float sj0 = sq[col0];
    float sj1 = sq[col1];
    int gtn = gtauI[myrow];

    __builtin_amdgcn_wave_barrier();
    {  // drain prev chunk: every lane owns row l   (prio 0: VALU/LDS phase)
      const int c = cntS[w][l];
      if (c) {
        const float* bD = &bufD[w][l * 33];
        const ushort* bI = &bufI[w][l * 34];
#pragma unroll 1
        for (int j = 0; j < c; ++j) {
          float d = bD[j];
          int ii = (int)bI[j];
          TOPK_INSERT(d, ii);
        }
        cntS[w][l] = 0;
      }
      tauS[w][l] = fminf(bmax, __int_as_float(gt));
      if (bmax < lastPub) {  // publish only on improvement
        atomicMin(&gtauI[myrow], __float_as_int(bmax));
        lastPub = bmax;
      }
    }
    __builtin_amdgcn_wave_barrier();
    gt = gtn;

#pragma unroll
    for (int rt = 0; rt < 4; ++rt) {
      f32x4 taur = *(const f32x4*)&tauS[w][rt * 16 + g * 4];
      __builtin_amdgcn_s_setprio(1);  // MFMA cluster: favor this wave's issue
      f32x4 acc0 = {0.f, 0.f, 0.f, 0.f};
      acc0 = __builtin_amdgcn_mfma_f32_16x16x32_bf16(aH1[rt], p0, acc0, 0, 0, 0);
      acc0 = __builtin_amdgcn_mfma_f32_16x16x32_bf16(aH2[rt], p1, acc0, 0, 0, 0);
      acc0 = __builtin_amdgcn_mfma_f32_16x16x32_bf16(aH1[rt], p2, acc0, 0, 0, 0);
      acc0 = __builtin_amdgcn_mfma_f32_16x16x32_bf16(aH2[rt], p3, acc0, 0, 0, 0);
      acc0 = __builtin_amdgcn_mfma_f32_16x16x32_bf16(aL1[rt], p0, acc0, 0, 0, 0);
      acc0 = __builtin_amdgcn_mfma_f32_16x16x32_bf16(aL2[rt], p1, acc0, 0, 0, 0);
      f32x4 acc1 = {0.f, 0.f, 0.f, 0.f};
      acc1 = __builtin_amdgcn_mfma_f32_16x16x32_bf16(aH1[rt], q0, acc1, 0, 0, 0);
      acc1 = __builtin_amdgcn_mfma_f32_16x16x32_bf16(aH2[rt], q1, acc1, 0, 0, 0);
      acc1 = __builtin_amdgcn_mfma_f32_16x16x32_bf16(aH1[rt], q2, acc1, 0, 0, 0);
      acc1 = __builtin_amdgcn_mfma_f32_16x16x32_bf16(aH2[rt], q3, acc1, 0, 0, 0);
      acc1 = __builtin_amdgcn_mfma_f32_16x16x32_bf16(aL1[rt], q0, acc1, 0, 0, 0);
      acc1 = __builtin_amdgcn_mfma_f32_16x16x32_bf16(aL2[rt], q1, acc1, 0, 0, 0);
      __builtin_amdgcn_s_setprio(0);  // epilogue/insert storm: yield issue
#pragma unroll
      for (int r = 0; r < 4; ++r) {
        const int rloc = rt * 16 + g * 4 + r;
        float d0 = fmaf(-2.f, acc0[r], sqi[rt * 4 + r] + sj0);
        if (d0 < taur[r]) {
          int pos = atomicAdd(&cntS[w][rloc], 1);
          bufD[w][rloc * 33 + pos] = d0;
          bufI[w][rloc * 34 + pos] = (ushort)col0;
        }
        float d1 = fmaf(-2.f, acc1[r], sqi[rt * 4 + r] + sj1);
        if (d1 < taur[r]) {
          int pos = atomicAdd(&cntS[w][rloc], 1);
          bufD[w][rloc * 33 + pos] = d1;
          bufI[w][rloc * 34 + pos] = (ushort)col1;
        }
      }
    }
  }

  __builtin_amdgcn_wave_barrier();
  {  // final drain
    const int c = cntS[w][l];
    const float* bD = &bufD[w][l * 33];
    const ushort* bI = &bufI[w][l * 34];
#pragma unroll 1
    for (int j = 0; j < c; ++j) {
      float d = bD[j];
      int ii = (int)bI[j];
      TOPK_INSERT(d, ii);
    }
  }
  float* dp = dpart + ((size_t)cs * N + myrow) * 10;
  ushort* ip = ipart + ((size_t)cs * N + myrow) * 10;
#pragma unroll
  for (int s = 0; s < 10; ++s) { dp[s] = bd[s]; ip[s] = (ushort)bi[s]; }
}

// ---------- kNN for C=3, exact fp32 (cancellation-sensitive: keep fp32!) ----------
// VERBATIM r0 structure: 32-col chunks, single drain, capacity 33.
__global__ __launch_bounds__(256, 3) void knn3g_kernel(const float4* __restrict__ xp,
                                                       int* __restrict__ gtauI,
                                                       float* __restrict__ dpart,
                                                       ushort* __restrict__ ipart) {
  __shared__ float bufD[4][64 * 33];
  __shared__ ushort bufI[4][64 * 34];
  __shared__ __align__(16) float tauS[4][64];
  __shared__ int cntS[4][64];

  const int tid = threadIdx.x;
  const int w = tid >> 6, l = tid & 63, lp = l & 15, g = l >> 4;
  const int rg = blockIdx.x / NS3, cs = blockIdx.x % NS3;
  const int wbase = rg * 256 + w * 64;
  const int myrow = wbase + l;
  const int c0 = (512 * cs) / NS3, c1 = (512 * (cs + 1)) / NS3;  // 32-col chunks

  tauS[w][l] = FBIG;
  cntS[w][l] = 0;
  __builtin_amdgcn_wave_barrier();

  float4 rw[16];
#pragma unroll
  for (int rt = 0; rt < 4; ++rt)
#pragma unroll
    for (int r = 0; r < 4; ++r) rw[rt * 4 + r] = xp[wbase + rt * 16 + g * 4 + r];

  float bd[10]; int bi[10]; float bmax = FBIG; float lastPub = FBIG;
#pragma unroll
  for (int s = 0; s < 10; ++s) { bd[s] = FBIG; bi[s] = 0x7fffffff; }
  int gt = 0x7F7F7F7F;

  for (int t = c0; t < c1; ++t) {
    const int col0 = t * 32 + lp;
    const int col1 = col0 + 16;
    const float4 oc0 = xp[col0];
    const float4 oc1 = xp[col1];
    int gtn = gtauI[myrow];

    __builtin_amdgcn_wave_barrier();
    {  // drain prev chunk
      const int c = cntS[w][l];
      if (c) {
        const float* bD = &bufD[w][l * 33];
        const ushort* bI = &bufI[w][l * 34];
#pragma unroll 1
        for (int j = 0; j < c; ++j) {
          float d = bD[j];
          int ii = (int)bI[j];
          TOPK_INSERT(d, ii);
        }
        cntS[w][l] = 0;
      }
      tauS[w][l] = fminf(bmax, __int_as_float(gt));
      if (bmax < lastPub) {
        atomicMin(&gtauI[myrow], __float_as_int(bmax));
        lastPub = bmax;
      }
    }
    __builtin_amdgcn_wave_barrier();
    gt = gtn;

#pragma unroll
    for (int rt = 0; rt < 4; ++rt) {
      f32x4 taur = *(const f32x4*)&tauS[w][rt * 16 + g * 4];
#pragma unroll
      for (int r = 0; r < 4; ++r) {
        const float4 m = rw[rt * 4 + r];
        const int rloc = rt * 16 + g * 4 + r;
        float dot0 = fmaf(m.x, oc0.x, fmaf(m.y, oc0.y, m.z * oc0.z));
        float d0 = fmaf(-2.f, dot0, m.w + oc0.w);  // same chain as validated knn3
        if (d0 < taur[r]) {
          int pos = atomicAdd(&cntS[w][rloc], 1);
          bufD[w][rloc * 33 + pos] = d0;
          bufI[w][rloc * 34 + pos] = (ushort)col0;
        }
        float dot1 = fmaf(m.x, oc1.x, fmaf(m.y, oc1.y, m.z * oc1.z));
        float d1 = fmaf(-2.f, dot1, m.w + oc1.w);
        if (d1 < taur[r]) {
          int pos = atomicAdd(&cntS[w][rloc], 1);
          bufD[w][rloc * 33 + pos] = d1;
          bufI[w][rloc * 34 + pos] = (ushort)col1;
        }
      }
    }
  }

  __builtin_amdgcn_wave_barrier();
  {  // final drain
    const int c = cntS[w][l];
    const float* bD = &bufD[w][l * 33];
    const ushort* bI = &bufI[w][l * 34];
#pragma unroll 1
    for (int j = 0; j < c; ++j) {
      float d = bD[j];
      int ii = (int)bI[j];
      TOPK_INSERT(d, ii);
    }
  }
  float* dp = dpart + ((size_t)cs * N + myrow) * 10;
  ushort* ip = ipart + ((size_t)cs * N + myrow) * 10;
#pragma unroll
  for (int s = 0; s < 10; ++s) { dp[s] = bd[s]; ip[s] = (ushort)bi[s]; }
}

// ---------- FUSED: merge ∥ uv ∥ (optional) pool-of-previous-feature ----------
// r11 WIN structure + r12 pool tail. Block roles:
//   [0, N/256)                : merge (flat r0 body)
//   [N/256, N/256+N/4)        : uv (r0 body, 4 points/block)
//   [N/256+N/4, +64)          : pool fprev into Pp at channel offset foff
// All bodies verbatim from their measured-good standalone forms. Pool of f_i
// rides on layer i+1's mergeuv (f_i complete by then) — hidden under uv.
template <int S>
__global__ __launch_bounds__(256) void mergeuv_kernel(const float* __restrict__ dpart,
                                                      const ushort* __restrict__ ipart,
                                                      ushort* __restrict__ idx_out,
                                                      const float* __restrict__ Xf, int CIN,
                                                      const float* __restrict__ W,
                                                      const float* __restrict__ bias,
                                                      float* __restrict__ U,
                                                      float* __restrict__ V,
                                                      const float* __restrict__ fprev,
                                                      int foff,
                                                      const int* __restrict__ n_pts,
                                                      float* __restrict__ Pp) {
  __shared__ float Ws[8192];  // used by uv branch only (2*CIN*64 floats, max 32KB)
  if (blockIdx.x < N / 256) {
    // ---- merge branch: flat r0 body ----
    const int row = blockIdx.x * 256 + threadIdx.x;
    float d[S * 10]; int id_[S * 10];
#pragma unroll
    for (int p = 0; p < S; ++p)
#pragma unroll
      for (int s = 0; s < 10; ++s) {
        d[p * 10 + s] = dpart[((size_t)p * N + row) * 10 + s];
        id_[p * 10 + s] = (int)ipart[((size_t)p * N + row) * 10 + s];
      }
#pragma unroll
    for (int t = 0; t < 10; ++t) {
      float dm = d[0]; int im = id_[0]; int slot = 0;
#pragma unroll
      for (int e = 1; e < S * 10; ++e) {
        bool better = (d[e] < dm) || (d[e] == dm && id_[e] < im);
        if (better) { dm = d[e]; im = id_[e]; slot = e; }
      }
      idx_out[(size_t)row * 10 + t] = (ushort)im;
#pragma unroll
      for (int e = 0; e < S * 10; ++e)
        if (e == slot) d[e] = FBIG;
    }
  } else if (blockIdx.x < N / 256 + N / 4) {
    // ---- uv branch: r0 body (4 points/block) ----
    const int bb = blockIdx.x - N / 256;
    int tid = threadIdx.x;
    int c = tid & 63, p = tid >> 6;
    int n = bb * 4 + p;
    const int tot = CIN * 128;
    for (int i = tid; i < tot; i += 256) Ws[i] = W[i];
    __syncthreads();
    const float* xr = Xf + (size_t)n * CIN;
    float vt = 0.f, vb = 0.f;
    for (int m = 0; m < CIN; ++m) {
      float xm = xr[m];
      vt = fmaf(xm, Ws[m * 64 + c], vt);
      vb = fmaf(xm, Ws[(CIN + m) * 64 + c], vb);
    }
    U[(size_t)n * 64 + c] = vb;
    V[(size_t)n * 64 + c] = vt - vb + bias[c];
  } else {
    // ---- pool branch: fprev -> Pp[q][b][foff..foff+63]  (pool1 body verbatim) ----
    int b = blockIdx.x - (N / 256 + N / 4);
    int tid = threadIdx.x;
    int q = tid >> 6, ch = tid & 63;
    int off = 0;
    for (int i = 0; i < b; ++i) off += n_pts[i];
    int cnt_ = n_pts[b];
    int s0 = off + (cnt_ * q) / 4;
    int s1 = off + (cnt_ * (q + 1)) / 4;
    float mx = -3.4e38f;
    for (int t = s0; t < s1; ++t) mx = fmaxf(mx, fprev[(size_t)t * 64 + ch]);
    Pp[((size_t)q * 64 + b) * 256 + foff + ch] = mx;
  }
}

// ---------- pool f4 (standalone; runs before head) ----------
__global__ __launch_bounds__(256) void pool4_kernel(const float* __restrict__ f4,
                                                    const int* __restrict__ n_pts,
                                                    float* __restrict__ Pp) {
  int b = blockIdx.x;
  int tid = threadIdx.x;
  int q = tid >> 6, ch = tid & 63;
  int off = 0;
  for (int i = 0; i < b; ++i) off += n_pts[i];
  int cnt_ = n_pts[b];
  int s0 = off + (cnt_ * q) / 4;
  int s1 = off + (cnt_ * (q + 1)) / 4;
  float mx = -3.4e38f;
  for (int t = s0; t < s1; ++t) mx = fmaxf(mx, f4[(size_t)t * 64 + ch]);
  Pp[((size_t)q * 64 + b) * 256 + 192 + ch] = mx;
}

// ---------- BN batch stats + last-block bnfin (r12) ----------
// Ticket pattern: per-block atomicAdds -> __syncthreads() (drains vmcnt, adds
// complete at coherence point) -> tid0 __threadfence + ticket atomicAdd on
// accum[128]. Block #255 re-reads accumulators via atomicAdd(p, 0.f) (coherent
// RMW read — safe across XCD L2s), computes scale/shift with the EXACT bnfin
// arithmetic, then resets accum + ticket for the next BN layer.
__global__ __launch_bounds__(256) void stats_kernel(const float* __restrict__ U,
                                                    const float* __restrict__ V,
                                                    const ushort* __restrict__ idx,
                                                    float* __restrict__ accum,
                                                    const float* __restrict__ gamma,
                                                    const float* __restrict__ beta,
                                                    float* __restrict__ scale,
                                                    float* __restrict__ shift) {
  int tid = threadIdx.x;
  int c = tid & 63, p = tid >> 6;
  int base = blockIdx.x * 64;  // 256 blocks x 64 points
  float s = 0.f, s2 = 0.f;
  for (int ch = 0; ch < 16; ++ch) {
    int n = base + ch * 4 + p;
    float vn = V[(size_t)n * 64 + c];
    const ushort* in_ = idx + (size_t)n * 10;
#pragma unroll
    for (int k = 0; k < 10; ++k) {
      float h = vn + U[(size_t)in_[k] * 64 + c];
      s += h;
      s2 = fmaf(h, h, s2);
    }
  }
  __shared__ float red[256], red2[256];
  red[tid] = s; red2[tid] = s2;
  __syncthreads();
  if (tid < 64) {
    float ts = red[tid] + red[64 + tid] + red[128 + tid] + red[192 + tid];
    float t2 = red2[tid] + red2[64 + tid] + red2[128 + tid] + red2[192 + tid];
    atomicAdd(&accum[tid], ts);
    atomicAdd(&accum[64 + tid], t2);
  }
  // ---- last-block bnfin ----
  __shared__ int lastFlag;
  __syncthreads();  // drains this block's atomic adds (vmcnt(0) before barrier)
  if (tid == 0) {
    __threadfence();
    unsigned t = atomicAdd((unsigned int*)&accum[128], 1u);
    lastFlag = (t == 255u) ? 1 : 0;
  }
  __syncthreads();
  if (lastFlag && tid < 64) {
    float sAll = atomicAdd(&accum[tid], 0.f);        // coherent read
    float s2All = atomicAdd(&accum[64 + tid], 0.f);  // coherent read
    float inv = 1.f / (float)(N * KNN);
    float mu = sAll * inv;
    float var = s2All * inv - mu * mu;
    float sc = gamma[tid] * rsqrtf(var + 1e-5f);
    scale[tid] = sc;
    shift[tid] = fmaf(-mu, sc, beta[tid]);
    accum[tid] = 0.f;                                // reset for next BN layer
    accum[64 + tid] = 0.f;
    if (tid == 0) *(unsigned int*)&accum[128] = 0u;  // reset ticket
  }
}

// ---------- apply (BN) + ReLU + max over k, FUSED with next layer's prep ----------
// r8 WIN: prep128s eliminated; numerics identical to the standalone prep.
__global__ __launch_bounds__(256) void apply_kernel(const float* __restrict__ U,
                                                    const float* __restrict__ V,
                                                    const ushort* __restrict__ idx,
                                                    const float* __restrict__ scale,
                                                    const float* __restrict__ shift,
                                                    int use_bn,
                                                    float* __restrict__ Fout,
                                                    ushort* __restrict__ Xp,
                                                    float* __restrict__ sq,
                                                    int* __restrict__ gtauI,
                                                    float* __restrict__ accum,
                                                    int do_prep) {
  int tid = threadIdx.x;
  int c = tid & 63, p = tid >> 6;
  int n = blockIdx.x * 4 + p;
  float sc = use_bn ? scale[c] : 1.f;
  float sh = use_bn ? shift[c] : 0.f;
  float vn = V[(size_t)n * 64 + c];
  const ushort* in_ = idx + (size_t)n * 10;
  float m = 0.f;
#pragma unroll
  for (int k = 0; k < 10; ++k) {
    float h = vn + U[(size_t)in_[k] * 64 + c];
    m = fmaxf(m, fmaf(h, sc, sh));
  }
  Fout[(size_t)n * 64 + c] = m;
  if (do_prep) {
    // bf16 hi/lo split (identical ops to prep128s)
    ushort hh = bf16_rne(m);
    ushort ll = bf16_rne(m - bf16_to_f(hh));
    Xp[(size_t)n * 128 + c] = hh;
    Xp[(size_t)n * 128 + 64 + c] = ll;
    // sq: per-4-channel exact chain (channel order), then 16-group butterfly
    int base = c & ~3;
    float v0 = __shfl(m, base + 0, 64);
    float v1 = __shfl(m, base + 1, 64);
    float v2 = __shfl(m, base + 2, 64);
    float v3 = __shfl(m, base + 3, 64);
    float ps = fmaf(v0, v0, fmaf(v1, v1, fmaf(v2, v2, v3 * v3)));
#pragma unroll
    for (int mm = 4; mm <= 32; mm <<= 1) ps += __shfl_xor(ps, mm, 64);
    if (c == 0) {
      sq[n] = ps;
      gtauI[n] = 0x7F7F7F7F;
    }
    if (blockIdx.x == 0 && tid < 132) accum[tid] = 0.f;  // incl. ticket (idempotent)
  }
}

// ---------- head: 4-way pool max + tanh(P@Wp + bp) + L2 normalize ----------
__global__ __launch_bounds__(128) void head_kernel(const float* __restrict__ Pp,
                                                   const float* __restrict__ Wp,
                                                   const float* __restrict__ bp,
                                                   float* __restrict__ out) {
  int b = blockIdx.x;
  int c = threadIdx.x;
  __shared__ float ps[256];
#pragma unroll
  for (int j = 0; j < 2; ++j) {
    int cc = c + j * 128;
    float m = Pp[(size_t)b * 256 + cc];
#pragma unroll
    for (int q = 1; q < 4; ++q) m = fmaxf(m, Pp[((size_t)q * 64 + b) * 256 + cc]);
    ps[cc] = m;
  }
  __syncthreads();
  float acc = bp[c];
  for (int m = 0; m < 256; ++m) acc = fmaf(ps[m], Wp[m * 128 + c], acc);
  float t = tanhf(acc);
  __shared__ float red[128];
  red[c] = t * t;
  __syncthreads();
  for (int s = 64; s > 0; s >>= 1) {
    if (c < s) red[c] += red[c + s];
    __syncthreads();
  }
  float nrm = sqrtf(red[0]);
  out[b * 128 + c] = t / (nrm + 1e-9f);
}

extern "C" void kernel_launch(void* const* d_in, const int* in_sizes, int n_in,
                              void* d_out, int out_size, void* d_ws, size_t ws_size,
                              hipStream_t stream) {
  const float* x = (const float*)d_in[0];
  const int* n_pts = (const int*)d_in[1];
  const float* W1 = (const float*)d_in[2];
  const float* b1 = (const float*)d_in[3];
  const float* g1 = (const float*)d_in[4];
  const float* be1 = (const float*)d_in[5];
  const float* W2 = (const float*)d_in[6];
  const float* b2 = (const float*)d_in[7];
  const float* W3 = (const float*)d_in[8];
  const float* b3 = (const float*)d_in[9];
  const float* g3 = (const float*)d_in[10];
  const float* be3 = (const float*)d_in[11];
  const float* W4 = (const float*)d_in[12];
  const float* b4 = (const float*)d_in[13];
  const float* Wp = (const float*)d_in[14];
  const float* bp = (const float*)d_in[15];
  float* out = (float*)d_out;

  char* w = (char*)d_ws;
  auto alloc = [&](size_t bytes) {
    char* p = w;
    w += (bytes + 255) & ~(size_t)255;
    return p;
  };
  const size_t FS = (size_t)N * 64 * 4;
  float* f1 = (float*)alloc(FS);
  float* f2 = (float*)alloc(FS);
  float* f3 = (float*)alloc(FS);
  float* f4 = (float*)alloc(FS);
  float* Ub = (float*)alloc(FS);
  float* Vb = (float*)alloc(FS);                              // own buffer —
                                                              // merge reads dpart WHILE uv writes V
  ushort* Xp128 = (ushort*)alloc((size_t)N * 128 * 2);        // 4 MB (own buffer;
                                                              // apply reads U while writing Xp)
  float* dpartf = (float*)alloc((size_t)NS64 * N * 10 * 4);   // 7.86 MB
  ushort* iparti = (ushort*)alloc((size_t)NS64 * N * 10 * 2); // 3.93 MB
  float4* xp = (float4*)alloc((size_t)N * 16);
  float* sqb = (float*)alloc((size_t)N * 4);
  int* gtauI = (int*)alloc((size_t)N * 4);
  ushort* idxb = (ushort*)alloc((size_t)N * 10 * 2);
  float* accum = (float*)alloc(1024);                         // 128 sums + ticket @128
  float* scaleb = (float*)alloc(256);
  float* shiftb = (float*)alloc(256);
  float* Ppart = (float*)alloc((size_t)4 * 64 * 256 * 4);
  (void)ws_size; (void)n_in; (void)in_sizes; (void)out_size;

  auto run_layer = [&](const float* fin, int cin, const float* W, const float* b,
                       const float* g, const float* be, int use_bn, int do_prep,
                       const float* fprev, int foff, float* fout) {
    const int mgrid = N / 256 + N / 4 + (fprev ? 64 : 0);
    if (cin == 3) {
      pack3_kernel<<<N / 256, 256, 0, stream>>>(fin, xp, gtauI, accum);
      knn3g_kernel<<<64 * NS3, 256, 0, stream>>>(xp, gtauI, dpartf, iparti);
      mergeuv_kernel<NS3><<<mgrid, 256, 0, stream>>>(dpartf, iparti, idxb,
                                                     fin, cin, W, b, Ub, Vb,
                                                     fprev, foff, n_pts, Ppart);
    } else {
      // Xp128/sq/gtauI already written by the PREVIOUS layer's fused apply
      knn64w_kernel<<<64 * NS64, 256, 0, stream>>>(Xp128, sqb, gtauI, dpartf, iparti);
      mergeuv_kernel<NS64><<<mgrid, 256, 0, stream>>>(dpartf, iparti, idxb,
                                                      fin, cin, W, b, Ub, Vb,
                                                      fprev, foff, n_pts, Ppart);
    }
    if (use_bn) {
      stats_kernel<<<256, 256, 0, stream>>>(Ub, Vb, idxb, accum, g, be, scaleb, shiftb);
    }
    apply_kernel<<<N / 4, 256, 0, stream>>>(Ub, Vb, idxb, scaleb, shiftb, use_bn,
                                            fout, Xp128, sqb, gtauI, accum, do_prep);
  };

  run_layer(x, 3, W1, b1, g1, be1, 1, 1, nullptr, 0, f1);
  run_layer(f1, 64, W2, b2, nullptr, nullptr, 0, 1, f1, 0, f2);
  run_layer(f2, 64, W3, b3, g3, be3, 1, 1, f2, 64, f3);
  run_layer(f3, 64, W4, b4, nullptr, nullptr, 0, 0, f3, 128, f4);
  pool4_kernel<<<64, 256, 0, stream>>>(f4, n_pts, Ppart);
  head_kernel<<<64, 128, 0, stream>>>(Ppart, Wp, bp, out);
}